// Round 8
// baseline (362.630 us; speedup 1.0000x reference)
//
#include <hip/hip_runtime.h>

// Path signature depth 5, d=10, L=128, B=256 — Abel-summed vector GEMM,
// immediate-offset LDS edition.
//
// Per (b,g) block (grid 2560): scan lanes (tid<100) carry s1,s2,s3 and emit
// W1/W0 Horner panels; GEMM lanes (tid<250) own 4 rows j=tid+250r of the
// 1000 (m3,c4) pairs:   C4 = S4 + 0.5*W0*d[c4];  S4 += W1*d[c4];
//                       acc[e] += C4 * d[e]   (level 5, K=127)
// level4 = final S4 (free). NSEG padded to 128 (zero delta = no-op) so both
// inner loops fully unroll at KC=16 -> every ds_read uses base+immediate
// (m3r[r] = tid/10 + 25r shares one base; offsets kl*800+r*200). W panel is
// float2-packed and double-buffered: 1 barrier per chunk.

#define D10    10
#define LPATH  128
#define NSEG   127
#define NSEGP  128         // padded (segment 127 = identity)
#define BLOCK  256
#define KC     16
#define NCH    8
#define RS     12          // dT row stride (floats, 48B)
#define OUT_PER_B 111110

__global__ __launch_bounds__(BLOCK, 4) void sig_kernel(
        const float* __restrict__ path,   // [B][D10][LPATH]
        float* __restrict__ out)          // [B][OUT_PER_B]
{
    __shared__ __align__(16) float dT[NSEGP * RS];     // 6.1 KB
    __shared__ __align__(16) float2 Wp[2][KC * 100];   // 25.6 KB (dbuf)

    const int tid = threadIdx.x;
    const int bb  = blockIdx.x;
    const int b   = bb / 10;
    const int g   = bb - b * 10;
    const float* pb = path + (size_t)b * (D10 * LPATH);

    // ---- delta table + zero pad row ----
    for (int idx = tid; idx < NSEG * D10; idx += BLOCK) {
        int t = idx / D10, c = idx - t * D10;
        dT[t * RS + c] = pb[c * LPATH + t + 1] - pb[c * LPATH + t];
    }
    if (tid < RS) dT[NSEG * RS + tid] = 0.f;
    __syncthreads();

    const int c2 = tid / 10;          // scan: c2 (tid<100); GEMM: m3 base /  -
    const int c3 = tid - c2 * 10;     // scan: c3; GEMM: c4

    float s1 = 0.f, s2 = 0.f, s3 = 0.f;   // levels 1-3 scan state (tid<100)
    float S4r[4] = {0.f, 0.f, 0.f, 0.f};  // level-4 prefix rows (tid<250)
    float acc[4][10];
#pragma unroll
    for (int r = 0; r < 4; r++)
#pragma unroll
        for (int e = 0; e < 10; e++) acc[r][e] = 0.f;

    for (int ch = 0; ch < NCH; ch++) {
        float2* wp = Wp[ch & 1];
        const float* dbase = &dT[ch * (KC * RS)];

        if (tid < 100) {
            const float* drg = dbase + g;
            const float* dr2 = dbase + c2;
            const float* dr3 = dbase + c3;
            float2* wpo = wp + tid;
#pragma unroll
            for (int kl = 0; kl < KC; kl++) {
                float dg  = drg[kl * RS];
                float dc2 = dr2[kl * RS];
                float dc3 = dr3[kl * RS];
                float u24 = s2 + (s1 + dg * 0.25f)       * dc2 * (1.f / 3.f);
                float u25 = s2 + (s1 + dg * 0.2f)        * dc2 * 0.25f;
                float u23 = s2 + (s1 + dg * (1.f / 3.f)) * dc2 * 0.5f;
                wpo[kl * 100] = make_float2(s3 + u24 * dc3 * 0.5f,
                                            s3 + u25 * dc3 * (1.f / 3.f));
                s3 += u23 * dc3;
                s2 += (s1 + dg * 0.5f) * dc2;
                s1 += dg;
            }
        }
        __syncthreads();   // W panel ready; other buffer free for next scan

        if (tid < 250) {
            const float2* wb = wp + c2;       // + kl*100 + 25*r immediates
            const float*  dc = dbase + c3;    // + kl*RS immediates
#pragma unroll
            for (int kl = 0; kl < KC; kl++) {
                const float* dr = dbase + kl * RS;
                float4 dA = *(const float4*)dr;
                float4 dB = *(const float4*)(dr + 4);
                float2 dC = *(const float2*)(dr + 8);
                float de[10] = {dA.x, dA.y, dA.z, dA.w,
                                dB.x, dB.y, dB.z, dB.w, dC.x, dC.y};
                float dc4v = dc[kl * RS];
                float hd   = 0.5f * dc4v;
#pragma unroll
                for (int r = 0; r < 4; r++) {
                    float2 w = wb[kl * 100 + 25 * r];
                    float c4v = S4r[r] + w.y * hd;
                    S4r[r] += w.x * dc4v;
#pragma unroll
                    for (int e = 0; e < 10; e++) acc[r][e] += c4v * de[e];
                }
            }
        }
    }

    // ---- epilogue (register state only) ----
    float* ob = out + (size_t)b * OUT_PER_B;
    if (tid < 100) {
        ob[110 + g * 100 + tid] = s3;               // level 3 (m3 = tid)
        if (c3 == 0) ob[10 + g * 10 + c2] = s2;     // level 2
        if (tid == 0) ob[g] = s1;                   // level 1
    }
    if (tid < 250) {
#pragma unroll
        for (int r = 0; r < 4; r++) {
            const int j = tid + 250 * r;            // = m3*10 + c4
            ob[1110 + g * 1000 + j] = S4r[r];       // level 4
            float* o5 = ob + 11110 + (size_t)g * 10000 + (size_t)j * 10;
#pragma unroll
            for (int e = 0; e < 10; e += 2) {
                float2 vv = make_float2(acc[r][e], acc[r][e + 1]);
                *(float2*)&o5[e] = vv;              // level 5 (8B aligned)
            }
        }
    }
}

extern "C" void kernel_launch(void* const* d_in, const int* in_sizes, int n_in,
                              void* d_out, int out_size, void* d_ws, size_t ws_size,
                              hipStream_t stream) {
    const float* path = (const float*)d_in[0];
    float* out = (float*)d_out;
    int B = in_sizes[0] / (D10 * LPATH);   // 256
    sig_kernel<<<B * 10, BLOCK, 0, stream>>>(path, out);
}